// Round 7
// baseline (1418.649 us; speedup 1.0000x reference)
//
#include <hip/hip_runtime.h>

#define N_NODES  100000
#define N_EDGES  1600000
#define DIM      128
#define N_GRAPHS 512

#define BW       512                         // nodes per bucket
#define NBUCK    ((N_NODES + BW - 1) / BW)   // 196
#define CAP      12288                       // max edges per bucket (avg 8163, +45 sigma)
#define NB_CHUNK 4096

#define SLICE_U  ((size_t)N_NODES * 8)       // uints per slice (16 dims)
#define SLICE_S  ((size_t)N_NODES * 16)      // ushorts per slice

typedef short  bf16x8 __attribute__((ext_vector_type(8)));
typedef float  f32x4  __attribute__((ext_vector_type(4)));

__device__ inline ushort f2bf(float f) {  // round-to-nearest-even
    union { float f; unsigned u; } v; v.f = f;
    unsigned r = v.u + 0x7FFFu + ((v.u >> 16) & 1u);
    return (ushort)(r >> 16);
}
__device__ inline float bf2f_lo(unsigned u) { union { unsigned u; float f; } v; v.u = u << 16; return v.f; }
__device__ inline float bf2f_hi(unsigned u) { union { unsigned u; float f; } v; v.u = u & 0xFFFF0000u; return v.f; }

// ---------------- dtype conversion ----------------

// sliced layout: xs[slice][node][16 dims], slice = dim>>4. Prescaled by dinv.
__global__ __launch_bounds__(256) void cvt_x(const float* __restrict__ x,
                                             const float* __restrict__ dinv,
                                             ushort* __restrict__ xs) {
    int i = blockIdx.x * 256 + threadIdx.x;  // 1.6M units of 8 dims
    int node = i >> 4;
    int hs   = i & 15;           // half-slice index; dim0 = hs*8
    float d = dinv[node];
    const float* xp = x + (size_t)node * 128 + hs * 8;
    float4 v0 = *(const float4*)xp;
    float4 v1 = *(const float4*)(xp + 4);
    uint4 o;
    o.x = (uint)f2bf(v0.x * d) | ((uint)f2bf(v0.y * d) << 16);
    o.y = (uint)f2bf(v0.z * d) | ((uint)f2bf(v0.w * d) << 16);
    o.z = (uint)f2bf(v1.x * d) | ((uint)f2bf(v1.y * d) << 16);
    o.w = (uint)f2bf(v1.z * d) | ((uint)f2bf(v1.w * d) << 16);
    ushort* dst = xs + (size_t)(hs >> 1) * SLICE_S + (size_t)node * 16 + (hs & 1) * 8;
    *(uint4*)dst = o;
}

// WT[L][n][k] = Ws[L][k][n], bf16
__global__ __launch_bounds__(256) void cvt_w(const float* __restrict__ Ws,
                                             ushort* __restrict__ WT) {
    int idx = blockIdx.x * 256 + threadIdx.x;  // 65536 total
    int L = idx >> 14, n = (idx >> 7) & 127, k = idx & 127;
    WT[idx] = f2bf(Ws[(L << 14) + (k << 7) + n]);
}

// ---------------- CSR build via LDS-staged bucket sort ----------------

__global__ __launch_bounds__(256) void initb_kernel(int* __restrict__ bfill,
                                                    int* __restrict__ csr) {
    int t = threadIdx.x;
    if (t < NBUCK) bfill[t] = t * CAP;
    if (t == 255) csr[N_NODES] = N_EDGES;
}

__global__ __launch_bounds__(256) void bin_kernel(const int* __restrict__ row,
                                                  const int* __restrict__ col,
                                                  int* __restrict__ bfill,
                                                  unsigned* __restrict__ tmp) {
    __shared__ unsigned s_val[NB_CHUNK];
    __shared__ int s_dst[NB_CHUNK];
    __shared__ int s_hist[256], s_scan[256];
    __shared__ int s_excl[NBUCK], s_base[NBUCK], s_cur[NBUCK];
    int t = threadIdx.x;
    int e0 = blockIdx.x * NB_CHUNK;

    s_hist[t] = 0;
    __syncthreads();
#pragma unroll
    for (int k = 0; k < NB_CHUNK / 256; ++k) {
        int e = e0 + t + k * 256;
        if (e < N_EDGES) atomicAdd(&s_hist[col[e] >> 9], 1);
    }
    __syncthreads();
    int h = s_hist[t];
    s_scan[t] = h;
    __syncthreads();
    for (int o = 1; o < 256; o <<= 1) {
        int u = (t >= o) ? s_scan[t - o] : 0;
        __syncthreads();
        s_scan[t] += u;
        __syncthreads();
    }
    if (t < NBUCK) {
        int ex = s_scan[t] - h;
        s_excl[t] = ex;
        s_cur[t]  = ex;
        s_base[t] = atomicAdd(&bfill[t], h);
    }
    __syncthreads();
#pragma unroll
    for (int k = 0; k < NB_CHUNK / 256; ++k) {
        int e = e0 + t + k * 256;
        if (e < N_EDGES) {
            int r = row[e], c = col[e];
            int b = c >> 9;
            int p = atomicAdd(&s_cur[b], 1);
            int dst = s_base[b] + (p - s_excl[b]);
            int lim = (b + 1) * CAP;
            if (dst >= lim) dst = lim - 1;  // overflow clamp (statistically impossible)
            s_val[p] = ((unsigned)(c & (BW - 1)) << 17) | (unsigned)r;
            s_dst[p] = dst;
        }
    }
    __syncthreads();
    int sc = N_EDGES - e0; if (sc > NB_CHUNK) sc = NB_CHUNK;
#pragma unroll
    for (int k = 0; k < NB_CHUNK / 256; ++k) {
        int j = t + k * 256;
        if (j < sc) tmp[s_dst[j]] = s_val[j];
    }
}

__global__ __launch_bounds__(256) void bscan_kernel(const int* __restrict__ bfill,
                                                    int* __restrict__ bbase) {
    __shared__ int s[256];
    int t = threadIdx.x;
    int cnt = 0;
    if (t < NBUCK) {
        cnt = bfill[t] - t * CAP;
        if (cnt > CAP) cnt = CAP;
    }
    s[t] = cnt;
    __syncthreads();
    for (int o = 1; o < 256; o <<= 1) {
        int u = (t >= o) ? s[t - o] : 0;
        __syncthreads();
        s[t] += u;
        __syncthreads();
    }
    if (t < NBUCK) bbase[t] = s[t] - cnt;
}

__global__ __launch_bounds__(256) void sort_kernel(const unsigned* __restrict__ tmp,
                                                   const int* __restrict__ bfill,
                                                   const int* __restrict__ bbase,
                                                   int* __restrict__ csr,
                                                   float* __restrict__ dinv,
                                                   int* __restrict__ ssrc) {
    __shared__ int s_cnt[BW];
    __shared__ int s_pair[256];
    __shared__ int s_off[BW];
    __shared__ int s_cur[BW];
    __shared__ int s_stage[CAP];
    int b = blockIdx.x, t = threadIdx.x;
    int wbeg = b * BW;
    int wn = N_NODES - wbeg; if (wn > BW) wn = BW;
    int nE = bfill[b] - b * CAP; if (nE > CAP) nE = CAP;
    const unsigned* T = tmp + (size_t)b * CAP;
    int base = bbase[b];

    for (int i = t; i < BW; i += 256) s_cnt[i] = 0;
    __syncthreads();
    for (int i = t; i < nE; i += 256) atomicAdd(&s_cnt[T[i] >> 17], 1);
    __syncthreads();
    int a0 = s_cnt[2 * t], a1 = s_cnt[2 * t + 1];
    s_pair[t] = a0 + a1;
    __syncthreads();
    for (int o = 1; o < 256; o <<= 1) {
        int u = (t >= o) ? s_pair[t - o] : 0;
        __syncthreads();
        s_pair[t] += u;
        __syncthreads();
    }
    int pre = s_pair[t] - (a0 + a1);
    s_off[2 * t] = pre;      s_off[2 * t + 1] = pre + a0;
    s_cur[2 * t] = pre;      s_cur[2 * t + 1] = pre + a0;
    __syncthreads();
    for (int i = t; i < wn; i += 256) {
        csr[wbeg + i]  = base + s_off[i];
        dinv[wbeg + i] = rsqrtf((float)(s_cnt[i] + 1));  // +1 = self loop
    }
    for (int i = t; i < nE; i += 256) {
        unsigned v = T[i];
        int p = atomicAdd(&s_cur[v >> 17], 1);
        s_stage[p] = (int)(v & 0x1FFFFu);
    }
    __syncthreads();
    for (int i = t; i < nE; i += 256) ssrc[base + i] = s_stage[i];
}

__global__ __launch_bounds__(256) void bounds_kernel(const int* __restrict__ batch,
                                                     int* __restrict__ gstart) {
    int i = blockIdx.x * 256 + threadIdx.x;
    if (i >= N_NODES) return;
    int b  = batch[i];
    int bp = (i == 0) ? -1 : batch[i - 1];
    for (int g = bp + 1; g <= b; ++g) gstart[g] = i;
    if (i == N_NODES - 1) {
        for (int g = b + 1; g <= N_GRAPHS; ++g) gstart[g] = N_NODES;
    }
}

// ---------------- aggregate, XCD-sliced ----------------
// g sliced [8][N][16 bf16]. blockIdx&7 = slice -> XCD via round-robin dispatch;
// per-XCD gather working set = 3.2 MB (L2-resident). Wave = 1 node: 8 edge
// streams x 8 lanes (32 B slice-row per gather), 2-deep unroll = 16 in flight.
__global__ __launch_bounds__(256) void agg_kernel(const uint* __restrict__ g,
                                                  uint* __restrict__ out,
                                                  const int* __restrict__ csr,
                                                  const int* __restrict__ ssrc,
                                                  const float* __restrict__ dinv) {
    int slice = blockIdx.x & 7;
    int node  = (blockIdx.x >> 3) * 4 + (threadIdx.x >> 6);
    int lane  = threadIdx.x & 63;
    int strm  = lane >> 3;   // 0..7
    int d     = lane & 7;    // uint (dim pair) within slice row
    const uint* gs = g + (size_t)slice * SLICE_U;

    float a0 = 0.f, a1 = 0.f;
    if (strm == 0) {  // self loop
        uint v = gs[(size_t)node * 8 + d];
        a0 = bf2f_lo(v); a1 = bf2f_hi(v);
    }
    int beg = csr[node], end = csr[node + 1];
    int e = beg + strm;
    for (; e + 8 < end; e += 16) {
        int s0 = __builtin_nontemporal_load(ssrc + e);
        int s1 = __builtin_nontemporal_load(ssrc + e + 8);
        uint v0 = gs[(size_t)s0 * 8 + d];
        uint v1 = gs[(size_t)s1 * 8 + d];
        a0 += bf2f_lo(v0); a1 += bf2f_hi(v0);
        a0 += bf2f_lo(v1); a1 += bf2f_hi(v1);
    }
    for (; e < end; e += 8) {
        int s = __builtin_nontemporal_load(ssrc + e);
        uint v = gs[(size_t)s * 8 + d];
        a0 += bf2f_lo(v); a1 += bf2f_hi(v);
    }
    a0 += __shfl_xor(a0, 8);  a1 += __shfl_xor(a1, 8);
    a0 += __shfl_xor(a0, 16); a1 += __shfl_xor(a1, 16);
    a0 += __shfl_xor(a0, 32); a1 += __shfl_xor(a1, 32);
    if (strm == 0) {
        float dv = dinv[node];
        uint ov = (uint)f2bf(a0 * dv) | ((uint)f2bf(a1 * dv) << 16);
        __builtin_nontemporal_store(ov, out + (size_t)slice * SLICE_U + (size_t)node * 8 + d);
    }
}

// ---------------- GEMM via bf16 MFMA (sliced A in, sliced out) ----------------
// mode: 1 = relu + prescale by dinv[m] (layers 0-2), 0 = plain (layer 3)
__global__ __launch_bounds__(256) void gemm_mfma(const ushort* __restrict__ A,
                                                 const ushort* __restrict__ WT,
                                                 const float* __restrict__ bias,
                                                 const float* __restrict__ dinv,
                                                 ushort* __restrict__ out,
                                                 int mode) {
    int lane = threadIdx.x & 63;
    int wv   = threadIdx.x >> 6;
    int m0   = blockIdx.x * 64 + wv * 16;
    int l15  = lane & 15;
    int kq   = (lane >> 4) * 8;
    int mrow = m0 + l15;
    if (mrow >= N_NODES) mrow = N_NODES - 1;  // clamp; stores guarded

    f32x4 acc[8];
#pragma unroll
    for (int t = 0; t < 8; ++t) acc[t] = (f32x4){0.f, 0.f, 0.f, 0.f};

#pragma unroll
    for (int k0 = 0; k0 < 128; k0 += 32) {
        int k = k0 + kq;
        bf16x8 a = *(const bf16x8*)(A + (size_t)(k >> 4) * SLICE_S + (size_t)mrow * 16 + (k & 15));
#pragma unroll
        for (int t = 0; t < 8; ++t) {
            bf16x8 b = *(const bf16x8*)(WT + (size_t)(t * 16 + l15) * 128 + k0 + kq);
            acc[t] = __builtin_amdgcn_mfma_f32_16x16x32_bf16(a, b, acc[t], 0, 0, 0);
        }
    }

    int orow = m0 + (lane >> 4) * 4;
    float sc[4];
#pragma unroll
    for (int r = 0; r < 4; ++r) {
        int m = orow + r;
        sc[r] = (mode && m < N_NODES) ? dinv[m] : 1.0f;
    }
#pragma unroll
    for (int t = 0; t < 8; ++t) {
        float bv = bias[t * 16 + l15];
#pragma unroll
        for (int r = 0; r < 4; ++r) {
            int m = orow + r;
            if (m < N_NODES) {
                float v = acc[t][r] + bv;
                if (mode) v = fmaxf(v, 0.f) * sc[r];
                out[(size_t)t * SLICE_S + (size_t)m * 16 + l15] = f2bf(v);
            }
        }
    }
}

// ---------------- pooling + MLP head ----------------

__global__ __launch_bounds__(256) void pool_kernel(const ushort* __restrict__ h,
                                                   const int* __restrict__ gstart,
                                                   float* __restrict__ pooled) {
    __shared__ float part[4][128];
    int g = blockIdx.x;
    int s = gstart[g], e2 = gstart[g + 1];
    int p     = threadIdx.x & 63;   // uint index (2 dims)
    int which = threadIdx.x >> 6;
    const uint* hu = (const uint*)h + (size_t)(p >> 3) * SLICE_U + (p & 7);

    float a0 = 0.f, a1 = 0.f;
    for (int n = s + which; n < e2; n += 4) {
        uint v = hu[(size_t)n * 8];
        a0 += bf2f_lo(v);
        a1 += bf2f_hi(v);
    }
    part[which][2 * p]     = a0;
    part[which][2 * p + 1] = a1;
    __syncthreads();
    if (which == 0) {
        float c = fmaxf((float)(e2 - s), 1.0f);
        float t0 = part[0][2 * p] + part[1][2 * p] + part[2][2 * p] + part[3][2 * p];
        float t1 = part[0][2 * p + 1] + part[1][2 * p + 1] + part[2][2 * p + 1] + part[3][2 * p + 1];
        pooled[(size_t)g * 128 + 2 * p]     = t0 / c;
        pooled[(size_t)g * 128 + 2 * p + 1] = t1 / c;
    }
}

__global__ __launch_bounds__(128) void mlp_kernel(const float* __restrict__ pooled,
                                                  const float* __restrict__ w1,
                                                  const float* __restrict__ b1,
                                                  const float* __restrict__ w2,
                                                  const float* __restrict__ b2,
                                                  float* __restrict__ out) {
    __shared__ float mean[128];
    __shared__ float hid[100];
    int g = blockIdx.x;
    int t = threadIdx.x;
    mean[t] = pooled[(size_t)g * 128 + t];
    __syncthreads();
    if (t < 100) {
        float s = b1[t];
        for (int k = 0; k < 128; ++k) s = fmaf(mean[k], w1[k * 100 + t], s);
        hid[t] = fmaxf(s, 0.f);
    }
    __syncthreads();
    if (t < 4) {
        float s = b2[t];
        for (int j = 0; j < 100; ++j) s = fmaf(hid[j], w2[j * 4 + t], s);
        out[(size_t)g * 4 + t] = s;
    }
}

// ---------------- launch ----------------

extern "C" void kernel_launch(void* const* d_in, const int* in_sizes, int n_in,
                              void* d_out, int out_size, void* d_ws, size_t ws_size,
                              hipStream_t stream) {
    const float* x   = (const float*)d_in[0];
    const float* Ws  = (const float*)d_in[1];
    const float* bs  = (const float*)d_in[2];
    const float* w1  = (const float*)d_in[3];
    const float* b1  = (const float*)d_in[4];
    const float* w2  = (const float*)d_in[5];
    const float* b2  = (const float*)d_in[6];
    const int*   ei  = (const int*)d_in[7];
    const int*   bat = (const int*)d_in[8];
    float* outp = (float*)d_out;

    char* p = (char*)d_ws;
    auto take = [&](size_t bytes) -> void* {
        void* r = (void*)p;
        p += (bytes + 255) & ~(size_t)255;
        return r;
    };
    int*      csr    = (int*)take((size_t)(N_NODES + 1) * 4);
    float*    dinv   = (float*)take((size_t)N_NODES * 4);
    int*      bfill  = (int*)take((size_t)NBUCK * 4);
    int*      bbase  = (int*)take((size_t)NBUCK * 4);
    unsigned* tmp    = (unsigned*)take((size_t)NBUCK * CAP * 4);
    int*      ssrc   = (int*)take((size_t)N_EDGES * 4);
    ushort*   xb     = (ushort*)take((size_t)N_NODES * 128 * 2);
    ushort*   hb     = (ushort*)take((size_t)N_NODES * 128 * 2);
    ushort*   aggb   = (ushort*)take((size_t)N_NODES * 128 * 2);
    ushort*   WT     = (ushort*)take((size_t)4 * 128 * 128 * 2);
    float*    pooled = (float*)take((size_t)N_GRAPHS * 128 * 4);
    int*      gstart = (int*)take((size_t)(N_GRAPHS + 1) * 4);

    const int* row = ei;
    const int* col = ei + N_EDGES;

    initb_kernel<<<1, 256, 0, stream>>>(bfill, csr);
    bin_kernel<<<(N_EDGES + NB_CHUNK - 1) / NB_CHUNK, 256, 0, stream>>>(row, col, bfill, tmp);
    bscan_kernel<<<1, 256, 0, stream>>>(bfill, bbase);
    sort_kernel<<<NBUCK, 256, 0, stream>>>(tmp, bfill, bbase, csr, dinv, ssrc);
    cvt_x<<<(N_NODES * 16) / 256, 256, 0, stream>>>(x, dinv, xb);
    cvt_w<<<256, 256, 0, stream>>>(Ws, WT);
    bounds_kernel<<<(N_NODES + 255) / 256, 256, 0, stream>>>(bat, gstart);

    const ushort* hin = xb;
    for (int L = 0; L < 4; ++L) {
        agg_kernel<<<(N_NODES / 4) * 8, 256, 0, stream>>>(
            (const uint*)hin, (uint*)aggb, csr, ssrc, dinv);
        gemm_mfma<<<(N_NODES + 63) / 64, 256, 0, stream>>>(
            aggb, WT + (size_t)L * 128 * 128, bs + (size_t)L * 128, dinv, hb, (L < 3) ? 1 : 0);
        hin = hb;
    }
    pool_kernel<<<N_GRAPHS, 256, 0, stream>>>(hb, gstart, pooled);
    mlp_kernel<<<N_GRAPHS, 128, 0, stream>>>(pooled, w1, b1, w2, b2, outp);
}

// Round 9
// 548.148 us; speedup vs baseline: 2.5881x; 2.5881x over previous
//
#include <hip/hip_runtime.h>

#define N_NODES  100000
#define N_EDGES  1600000
#define DIM      128
#define N_GRAPHS 512

#define BW       512                         // nodes per bucket
#define NBUCK    ((N_NODES + BW - 1) / BW)   // 196
#define CAP      12288                       // max edges per bucket (avg 8163, +45 sigma)
#define NB_CHUNK 4096

typedef short  bf16x8 __attribute__((ext_vector_type(8)));
typedef float  f32x4  __attribute__((ext_vector_type(4)));

__device__ inline ushort f2bf(float f) {  // round-to-nearest-even
    union { float f; unsigned u; } v; v.f = f;
    unsigned r = v.u + 0x7FFFu + ((v.u >> 16) & 1u);
    return (ushort)(r >> 16);
}
__device__ inline float bf2f_lo(unsigned u) { union { unsigned u; float f; } v; v.u = u << 16; return v.f; }
__device__ inline float bf2f_hi(unsigned u) { union { unsigned u; float f; } v; v.u = u & 0xFFFF0000u; return v.f; }

// ---------------- dtype conversion ----------------

// xb[i] = bf16( x[i] * dinv[node] )  -- prescaled layer-0 input (row-major)
__global__ __launch_bounds__(256) void cvt_x(const float* __restrict__ x,
                                             const float* __restrict__ dinv,
                                             ushort* __restrict__ xb) {
    int i = (blockIdx.x * 256 + threadIdx.x) * 4;  // 12.8M elements, exact
    float d = dinv[i >> 7];
    float4 v = *(const float4*)(x + i);
    ushort4 o;
    o.x = f2bf(v.x * d); o.y = f2bf(v.y * d); o.z = f2bf(v.z * d); o.w = f2bf(v.w * d);
    *(ushort4*)(xb + i) = o;
}

// WT[L][n][k] = Ws[L][k][n], bf16
__global__ __launch_bounds__(256) void cvt_w(const float* __restrict__ Ws,
                                             ushort* __restrict__ WT) {
    int idx = blockIdx.x * 256 + threadIdx.x;  // 65536 total
    int L = idx >> 14, n = (idx >> 7) & 127, k = idx & 127;
    WT[idx] = f2bf(Ws[(L << 14) + (k << 7) + n]);
}

// ---------------- CSR build via LDS-staged bucket sort ----------------

__global__ __launch_bounds__(256) void initb_kernel(int* __restrict__ bfill,
                                                    int* __restrict__ csr) {
    int t = threadIdx.x;
    if (t < NBUCK) bfill[t] = t * CAP;
    if (t == 255) csr[N_NODES] = N_EDGES;
}

__global__ __launch_bounds__(256) void bin_kernel(const int* __restrict__ row,
                                                  const int* __restrict__ col,
                                                  int* __restrict__ bfill,
                                                  unsigned* __restrict__ tmp) {
    __shared__ unsigned s_val[NB_CHUNK];
    __shared__ int s_dst[NB_CHUNK];
    __shared__ int s_hist[256], s_scan[256];
    __shared__ int s_excl[NBUCK], s_base[NBUCK], s_cur[NBUCK];
    int t = threadIdx.x;
    int e0 = blockIdx.x * NB_CHUNK;

    s_hist[t] = 0;
    __syncthreads();
#pragma unroll
    for (int k = 0; k < NB_CHUNK / 256; ++k) {
        int e = e0 + t + k * 256;
        if (e < N_EDGES) atomicAdd(&s_hist[col[e] >> 9], 1);
    }
    __syncthreads();
    int h = s_hist[t];
    s_scan[t] = h;
    __syncthreads();
    for (int o = 1; o < 256; o <<= 1) {
        int u = (t >= o) ? s_scan[t - o] : 0;
        __syncthreads();
        s_scan[t] += u;
        __syncthreads();
    }
    if (t < NBUCK) {
        int ex = s_scan[t] - h;
        s_excl[t] = ex;
        s_cur[t]  = ex;
        s_base[t] = atomicAdd(&bfill[t], h);
    }
    __syncthreads();
#pragma unroll
    for (int k = 0; k < NB_CHUNK / 256; ++k) {
        int e = e0 + t + k * 256;
        if (e < N_EDGES) {
            int r = row[e], c = col[e];
            int b = c >> 9;
            int p = atomicAdd(&s_cur[b], 1);
            int dst = s_base[b] + (p - s_excl[b]);
            int lim = (b + 1) * CAP;
            if (dst >= lim) dst = lim - 1;  // overflow clamp (statistically impossible)
            s_val[p] = ((unsigned)(c & (BW - 1)) << 17) | (unsigned)r;
            s_dst[p] = dst;
        }
    }
    __syncthreads();
    int sc = N_EDGES - e0; if (sc > NB_CHUNK) sc = NB_CHUNK;
#pragma unroll
    for (int k = 0; k < NB_CHUNK / 256; ++k) {
        int j = t + k * 256;
        if (j < sc) tmp[s_dst[j]] = s_val[j];
    }
}

__global__ __launch_bounds__(256) void bscan_kernel(const int* __restrict__ bfill,
                                                    int* __restrict__ bbase) {
    __shared__ int s[256];
    int t = threadIdx.x;
    int cnt = 0;
    if (t < NBUCK) {
        cnt = bfill[t] - t * CAP;
        if (cnt > CAP) cnt = CAP;
    }
    s[t] = cnt;
    __syncthreads();
    for (int o = 1; o < 256; o <<= 1) {
        int u = (t >= o) ? s[t - o] : 0;
        __syncthreads();
        s[t] += u;
        __syncthreads();
    }
    if (t < NBUCK) bbase[t] = s[t] - cnt;
}

__global__ __launch_bounds__(256) void sort_kernel(const unsigned* __restrict__ tmp,
                                                   const int* __restrict__ bfill,
                                                   const int* __restrict__ bbase,
                                                   int* __restrict__ csr,
                                                   float* __restrict__ dinv,
                                                   int* __restrict__ ssrc) {
    __shared__ int s_cnt[BW];
    __shared__ int s_pair[256];
    __shared__ int s_off[BW];
    __shared__ int s_cur[BW];
    __shared__ int s_stage[CAP];
    int b = blockIdx.x, t = threadIdx.x;
    int wbeg = b * BW;
    int wn = N_NODES - wbeg; if (wn > BW) wn = BW;
    int nE = bfill[b] - b * CAP; if (nE > CAP) nE = CAP;
    const unsigned* T = tmp + (size_t)b * CAP;
    int base = bbase[b];

    for (int i = t; i < BW; i += 256) s_cnt[i] = 0;
    __syncthreads();
    for (int i = t; i < nE; i += 256) atomicAdd(&s_cnt[T[i] >> 17], 1);
    __syncthreads();
    int a0 = s_cnt[2 * t], a1 = s_cnt[2 * t + 1];
    s_pair[t] = a0 + a1;
    __syncthreads();
    for (int o = 1; o < 256; o <<= 1) {
        int u = (t >= o) ? s_pair[t - o] : 0;
        __syncthreads();
        s_pair[t] += u;
        __syncthreads();
    }
    int pre = s_pair[t] - (a0 + a1);
    s_off[2 * t] = pre;      s_off[2 * t + 1] = pre + a0;
    s_cur[2 * t] = pre;      s_cur[2 * t + 1] = pre + a0;
    __syncthreads();
    for (int i = t; i < wn; i += 256) {
        csr[wbeg + i]  = base + s_off[i];
        dinv[wbeg + i] = rsqrtf((float)(s_cnt[i] + 1));  // +1 = self loop
    }
    for (int i = t; i < nE; i += 256) {
        unsigned v = T[i];
        int p = atomicAdd(&s_cur[v >> 17], 1);
        s_stage[p] = (int)(v & 0x1FFFFu);
    }
    __syncthreads();
    for (int i = t; i < nE; i += 256) ssrc[base + i] = s_stage[i];
}

__global__ __launch_bounds__(256) void bounds_kernel(const int* __restrict__ batch,
                                                     int* __restrict__ gstart) {
    int i = blockIdx.x * 256 + threadIdx.x;
    if (i >= N_NODES) return;
    int b  = batch[i];
    int bp = (i == 0) ? -1 : batch[i - 1];
    for (int g = bp + 1; g <= b; ++g) gstart[g] = i;
    if (i == N_NODES - 1) {
        for (int g = b + 1; g <= N_GRAPHS; ++g) gstart[g] = N_NODES;
    }
}

// ---------------- aggregate: out[c] = dinv[c] * (g[c] + sum g[src]) ----------
// one wave per node; quarter-wave (16 lanes x 16 B) reads one 256 B row;
// 4 edges in flight per wave; fp32 accumulate.
__global__ __launch_bounds__(256) void agg_kernel(const ushort* __restrict__ g,
                                                  ushort* __restrict__ out,
                                                  const int* __restrict__ off,
                                                  const int* __restrict__ ssrc,
                                                  const float* __restrict__ dinv) {
    int node = blockIdx.x * 4 + (threadIdx.x >> 6);
    int lane = threadIdx.x & 63;
    int q = lane >> 4;
    int l = lane & 15;
    const uint4* hp = (const uint4*)g;  // row = 16 uint4 (256 B)

    float acc[8];
#pragma unroll
    for (int i = 0; i < 8; ++i) acc[i] = 0.f;

    if (q == 0) {  // self loop: + g[node]
        uint4 v = hp[(size_t)node * 16 + l];
        acc[0] = bf2f_lo(v.x); acc[1] = bf2f_hi(v.x);
        acc[2] = bf2f_lo(v.y); acc[3] = bf2f_hi(v.y);
        acc[4] = bf2f_lo(v.z); acc[5] = bf2f_hi(v.z);
        acc[6] = bf2f_lo(v.w); acc[7] = bf2f_hi(v.w);
    }

    int beg = off[node], end = off[node + 1];
    int e = beg + q;
    for (; e + 12 < end; e += 16) {
        int s0 = ssrc[e], s1 = ssrc[e + 4], s2 = ssrc[e + 8], s3 = ssrc[e + 12];
        uint4 v0 = hp[(size_t)s0 * 16 + l];
        uint4 v1 = hp[(size_t)s1 * 16 + l];
        uint4 v2 = hp[(size_t)s2 * 16 + l];
        uint4 v3 = hp[(size_t)s3 * 16 + l];
        acc[0] += bf2f_lo(v0.x); acc[1] += bf2f_hi(v0.x);
        acc[2] += bf2f_lo(v0.y); acc[3] += bf2f_hi(v0.y);
        acc[4] += bf2f_lo(v0.z); acc[5] += bf2f_hi(v0.z);
        acc[6] += bf2f_lo(v0.w); acc[7] += bf2f_hi(v0.w);
        acc[0] += bf2f_lo(v1.x); acc[1] += bf2f_hi(v1.x);
        acc[2] += bf2f_lo(v1.y); acc[3] += bf2f_hi(v1.y);
        acc[4] += bf2f_lo(v1.z); acc[5] += bf2f_hi(v1.z);
        acc[6] += bf2f_lo(v1.w); acc[7] += bf2f_hi(v1.w);
        acc[0] += bf2f_lo(v2.x); acc[1] += bf2f_hi(v2.x);
        acc[2] += bf2f_lo(v2.y); acc[3] += bf2f_hi(v2.y);
        acc[4] += bf2f_lo(v2.z); acc[5] += bf2f_hi(v2.z);
        acc[6] += bf2f_lo(v2.w); acc[7] += bf2f_hi(v2.w);
        acc[0] += bf2f_lo(v3.x); acc[1] += bf2f_hi(v3.x);
        acc[2] += bf2f_lo(v3.y); acc[3] += bf2f_hi(v3.y);
        acc[4] += bf2f_lo(v3.z); acc[5] += bf2f_hi(v3.z);
        acc[6] += bf2f_lo(v3.w); acc[7] += bf2f_hi(v3.w);
    }
    for (; e < end; e += 4) {
        int s = ssrc[e];
        uint4 v = hp[(size_t)s * 16 + l];
        acc[0] += bf2f_lo(v.x); acc[1] += bf2f_hi(v.x);
        acc[2] += bf2f_lo(v.y); acc[3] += bf2f_hi(v.y);
        acc[4] += bf2f_lo(v.z); acc[5] += bf2f_hi(v.z);
        acc[6] += bf2f_lo(v.w); acc[7] += bf2f_hi(v.w);
    }

#pragma unroll
    for (int i = 0; i < 8; ++i) {
        acc[i] += __shfl_xor(acc[i], 16);
        acc[i] += __shfl_xor(acc[i], 32);
    }
    if (q == 0) {
        float d = dinv[node];
        uint4 ov;
        ov.x = (uint)f2bf(acc[0] * d) | ((uint)f2bf(acc[1] * d) << 16);
        ov.y = (uint)f2bf(acc[2] * d) | ((uint)f2bf(acc[3] * d) << 16);
        ov.z = (uint)f2bf(acc[4] * d) | ((uint)f2bf(acc[5] * d) << 16);
        ov.w = (uint)f2bf(acc[6] * d) | ((uint)f2bf(acc[7] * d) << 16);
        ((uint4*)out)[(size_t)node * 16 + l] = ov;
    }
}

// ---------------- GEMM via bf16 MFMA, WT staged in LDS -----------------------
// block = 256 thr / 4 waves, tile 128 m x 128 n. WT (128x128 bf16 = 2048 uint4)
// staged ONCE per block into LDS: 256 thr x 8 iters, 16 B each. Row pad +8
// ushorts -> lane stride 68 dwords = 2-way bank aliasing (free, m136).
// mode: 1 = relu + prescale dinv (layers 0-2), 0 = plain (layer 3).
#define WPAD 136
__global__ __launch_bounds__(256) void gemm_mfma(const ushort* __restrict__ A,
                                                 const ushort* __restrict__ WT,
                                                 const float* __restrict__ bias,
                                                 const float* __restrict__ dinv,
                                                 ushort* __restrict__ out,
                                                 int mode) {
    __shared__ ushort sW[128 * WPAD];
    int t = threadIdx.x;
    {   // stage WT: 2048 uint4 transfers (16 per row), coalesced
#pragma unroll
        for (int j = 0; j < 8; ++j) {
            int idx = t + j * 256;      // 0..2047
            int r = idx >> 4, qq = idx & 15;
            uint4 v = *(const uint4*)(WT + (size_t)r * 128 + qq * 8);
            *(uint4*)(sW + (size_t)r * WPAD + qq * 8) = v;
        }
    }
    __syncthreads();

    int lane = t & 63;
    int wv   = t >> 6;
    int m0   = blockIdx.x * 128 + wv * 32;
    int l15  = lane & 15;
    int kq   = (lane >> 4) * 8;
    int r0 = m0 + l15, r1 = m0 + 16 + l15;
    if (r0 >= N_NODES) r0 = N_NODES - 1;  // clamp loads; stores guarded
    if (r1 >= N_NODES) r1 = N_NODES - 1;

    f32x4 acc0[8], acc1[8];
#pragma unroll
    for (int n = 0; n < 8; ++n) {
        acc0[n] = (f32x4){0.f, 0.f, 0.f, 0.f};
        acc1[n] = (f32x4){0.f, 0.f, 0.f, 0.f};
    }

#pragma unroll
    for (int k0 = 0; k0 < 128; k0 += 32) {
        bf16x8 a0 = *(const bf16x8*)(A + (size_t)r0 * 128 + k0 + kq);
        bf16x8 a1 = *(const bf16x8*)(A + (size_t)r1 * 128 + k0 + kq);
#pragma unroll
        for (int n = 0; n < 8; ++n) {
            bf16x8 b = *(const bf16x8*)(sW + (size_t)(n * 16 + l15) * WPAD + k0 + kq);
            acc0[n] = __builtin_amdgcn_mfma_f32_16x16x32_bf16(a0, b, acc0[n], 0, 0, 0);
            acc1[n] = __builtin_amdgcn_mfma_f32_16x16x32_bf16(a1, b, acc1[n], 0, 0, 0);
        }
    }

#pragma unroll
    for (int sub = 0; sub < 2; ++sub) {
        int orow = m0 + sub * 16 + (lane >> 4) * 4;
        float sc[4];
#pragma unroll
        for (int r = 0; r < 4; ++r) {
            int m = orow + r;
            sc[r] = (mode && m < N_NODES) ? dinv[m] : 1.0f;
        }
#pragma unroll
        for (int n = 0; n < 8; ++n) {
            int col = n * 16 + l15;
            float bv = bias[col];
            f32x4 av = sub ? acc1[n] : acc0[n];
#pragma unroll
            for (int r = 0; r < 4; ++r) {
                int m = orow + r;
                if (m < N_NODES) {
                    float v = av[r] + bv;
                    if (mode) v = fmaxf(v, 0.f) * sc[r];
                    out[(size_t)m * 128 + col] = f2bf(v);
                }
            }
        }
    }
}

// ---------------- pooling + MLP head ----------------

__global__ __launch_bounds__(256) void pool_kernel(const ushort* __restrict__ h,
                                                   const int* __restrict__ gstart,
                                                   float* __restrict__ pooled) {
    __shared__ float part[4][128];
    int g = blockIdx.x;
    int s = gstart[g], e2 = gstart[g + 1];
    int p     = threadIdx.x & 63;
    int which = threadIdx.x >> 6;
    const uint* hu = (const uint*)h;

    float a0 = 0.f, a1 = 0.f;
    for (int n = s + which; n < e2; n += 4) {
        uint v = hu[(size_t)n * 64 + p];
        a0 += bf2f_lo(v);
        a1 += bf2f_hi(v);
    }
    part[which][2 * p]     = a0;
    part[which][2 * p + 1] = a1;
    __syncthreads();
    if (which == 0) {
        float c = fmaxf((float)(e2 - s), 1.0f);
        float t0 = part[0][2 * p] + part[1][2 * p] + part[2][2 * p] + part[3][2 * p];
        float t1 = part[0][2 * p + 1] + part[1][2 * p + 1] + part[2][2 * p + 1] + part[3][2 * p + 1];
        pooled[(size_t)g * 128 + 2 * p]     = t0 / c;
        pooled[(size_t)g * 128 + 2 * p + 1] = t1 / c;
    }
}

__global__ __launch_bounds__(128) void mlp_kernel(const float* __restrict__ pooled,
                                                  const float* __restrict__ w1,
                                                  const float* __restrict__ b1,
                                                  const float* __restrict__ w2,
                                                  const float* __restrict__ b2,
                                                  float* __restrict__ out) {
    __shared__ float mean[128];
    __shared__ float hid[100];
    int g = blockIdx.x;
    int t = threadIdx.x;
    mean[t] = pooled[(size_t)g * 128 + t];
    __syncthreads();
    if (t < 100) {
        float s = b1[t];
        for (int k = 0; k < 128; ++k) s = fmaf(mean[k], w1[k * 100 + t], s);
        hid[t] = fmaxf(s, 0.f);
    }
    __syncthreads();
    if (t < 4) {
        float s = b2[t];
        for (int j = 0; j < 100; ++j) s = fmaf(hid[j], w2[j * 4 + t], s);
        out[(size_t)g * 4 + t] = s;
    }
}

// ---------------- launch ----------------

extern "C" void kernel_launch(void* const* d_in, const int* in_sizes, int n_in,
                              void* d_out, int out_size, void* d_ws, size_t ws_size,
                              hipStream_t stream) {
    const float* x   = (const float*)d_in[0];
    const float* Ws  = (const float*)d_in[1];
    const float* bs  = (const float*)d_in[2];
    const float* w1  = (const float*)d_in[3];
    const float* b1  = (const float*)d_in[4];
    const float* w2  = (const float*)d_in[5];
    const float* b2  = (const float*)d_in[6];
    const int*   ei  = (const int*)d_in[7];
    const int*   bat = (const int*)d_in[8];
    float* outp = (float*)d_out;

    char* p = (char*)d_ws;
    auto take = [&](size_t bytes) -> void* {
        void* r = (void*)p;
        p += (bytes + 255) & ~(size_t)255;
        return r;
    };
    int*      csr    = (int*)take((size_t)(N_NODES + 1) * 4);
    float*    dinv   = (float*)take((size_t)N_NODES * 4);
    int*      bfill  = (int*)take((size_t)NBUCK * 4);
    int*      bbase  = (int*)take((size_t)NBUCK * 4);
    unsigned* tmp    = (unsigned*)take((size_t)NBUCK * CAP * 4);
    int*      ssrc   = (int*)take((size_t)N_EDGES * 4);
    ushort*   xb     = (ushort*)take((size_t)N_NODES * 128 * 2);
    ushort*   hb     = (ushort*)take((size_t)N_NODES * 128 * 2);
    ushort*   aggb   = (ushort*)take((size_t)N_NODES * 128 * 2);
    ushort*   WT     = (ushort*)take((size_t)4 * 128 * 128 * 2);
    float*    pooled = (float*)take((size_t)N_GRAPHS * 128 * 4);
    int*      gstart = (int*)take((size_t)(N_GRAPHS + 1) * 4);

    const int* row = ei;
    const int* col = ei + N_EDGES;

    initb_kernel<<<1, 256, 0, stream>>>(bfill, csr);
    bin_kernel<<<(N_EDGES + NB_CHUNK - 1) / NB_CHUNK, 256, 0, stream>>>(row, col, bfill, tmp);
    bscan_kernel<<<1, 256, 0, stream>>>(bfill, bbase);
    sort_kernel<<<NBUCK, 256, 0, stream>>>(tmp, bfill, bbase, csr, dinv, ssrc);
    cvt_x<<<12500, 256, 0, stream>>>(x, dinv, xb);
    cvt_w<<<256, 256, 0, stream>>>(Ws, WT);
    bounds_kernel<<<(N_NODES + 255) / 256, 256, 0, stream>>>(bat, gstart);

    const ushort* hin = xb;
    for (int L = 0; L < 4; ++L) {
        agg_kernel<<<N_NODES / 4, 256, 0, stream>>>(hin, aggb, csr, ssrc, dinv);
        gemm_mfma<<<(N_NODES + 127) / 128, 256, 0, stream>>>(
            aggb, WT + (size_t)L * 128 * 128, bs + (size_t)L * 128, dinv, hb, (L < 3) ? 1 : 0);
        hin = hb;
    }
    pool_kernel<<<N_GRAPHS, 256, 0, stream>>>(hb, gstart, pooled);
    mlp_kernel<<<N_GRAPHS, 128, 0, stream>>>(pooled, w1, b1, w2, b2, outp);
}

// Round 10
// 516.293 us; speedup vs baseline: 2.7478x; 1.0617x over previous
//
#include <hip/hip_runtime.h>

#define N_NODES  100000
#define N_EDGES  1600000
#define DIM      128
#define N_GRAPHS 512

#define BW       512                         // nodes per bucket
#define NBUCK    ((N_NODES + BW - 1) / BW)   // 196
#define CAP      12288                       // max edges per bucket (avg 8163, +45 sigma)
#define NB_CHUNK 4096

typedef short  bf16x8 __attribute__((ext_vector_type(8)));
typedef float  f32x4  __attribute__((ext_vector_type(4)));

__device__ inline ushort f2bf(float f) {  // round-to-nearest-even
    union { float f; unsigned u; } v; v.f = f;
    unsigned r = v.u + 0x7FFFu + ((v.u >> 16) & 1u);
    return (ushort)(r >> 16);
}
__device__ inline float bf2f_lo(unsigned u) { union { unsigned u; float f; } v; v.u = u << 16; return v.f; }
__device__ inline float bf2f_hi(unsigned u) { union { unsigned u; float f; } v; v.u = u & 0xFFFF0000u; return v.f; }

// ---------------- dtype conversion ----------------

// xb[i] = bf16( x[i] * dinv[node] )  -- prescaled layer-0 input (row-major)
__global__ __launch_bounds__(256) void cvt_x(const float* __restrict__ x,
                                             const float* __restrict__ dinv,
                                             ushort* __restrict__ xb) {
    int i = (blockIdx.x * 256 + threadIdx.x) * 4;  // 12.8M elements, exact
    float d = dinv[i >> 7];
    float4 v = *(const float4*)(x + i);
    ushort4 o;
    o.x = f2bf(v.x * d); o.y = f2bf(v.y * d); o.z = f2bf(v.z * d); o.w = f2bf(v.w * d);
    *(ushort4*)(xb + i) = o;
}

// WT[L][n][k] = Ws[L][k][n], bf16
__global__ __launch_bounds__(256) void cvt_w(const float* __restrict__ Ws,
                                             ushort* __restrict__ WT) {
    int idx = blockIdx.x * 256 + threadIdx.x;  // 65536 total
    int L = idx >> 14, n = (idx >> 7) & 127, k = idx & 127;
    WT[idx] = f2bf(Ws[(L << 14) + (k << 7) + n]);
}

// ---------------- CSR build via LDS-staged bucket sort ----------------

__global__ __launch_bounds__(256) void initb_kernel(int* __restrict__ bfill,
                                                    int* __restrict__ csr) {
    int t = threadIdx.x;
    if (t < NBUCK) bfill[t] = t * CAP;
    if (t == 255) csr[N_NODES] = N_EDGES;
}

__global__ __launch_bounds__(256) void bin_kernel(const int* __restrict__ row,
                                                  const int* __restrict__ col,
                                                  int* __restrict__ bfill,
                                                  unsigned* __restrict__ tmp) {
    __shared__ unsigned s_val[NB_CHUNK];
    __shared__ int s_dst[NB_CHUNK];
    __shared__ int s_hist[256], s_scan[256];
    __shared__ int s_excl[NBUCK], s_base[NBUCK], s_cur[NBUCK];
    int t = threadIdx.x;
    int e0 = blockIdx.x * NB_CHUNK;

    s_hist[t] = 0;
    __syncthreads();
#pragma unroll
    for (int k = 0; k < NB_CHUNK / 256; ++k) {
        int e = e0 + t + k * 256;
        if (e < N_EDGES) atomicAdd(&s_hist[col[e] >> 9], 1);
    }
    __syncthreads();
    int h = s_hist[t];
    s_scan[t] = h;
    __syncthreads();
    for (int o = 1; o < 256; o <<= 1) {
        int u = (t >= o) ? s_scan[t - o] : 0;
        __syncthreads();
        s_scan[t] += u;
        __syncthreads();
    }
    if (t < NBUCK) {
        int ex = s_scan[t] - h;
        s_excl[t] = ex;
        s_cur[t]  = ex;
        s_base[t] = atomicAdd(&bfill[t], h);
    }
    __syncthreads();
#pragma unroll
    for (int k = 0; k < NB_CHUNK / 256; ++k) {
        int e = e0 + t + k * 256;
        if (e < N_EDGES) {
            int r = row[e], c = col[e];
            int b = c >> 9;
            int p = atomicAdd(&s_cur[b], 1);
            int dst = s_base[b] + (p - s_excl[b]);
            int lim = (b + 1) * CAP;
            if (dst >= lim) dst = lim - 1;  // overflow clamp (statistically impossible)
            s_val[p] = ((unsigned)(c & (BW - 1)) << 17) | (unsigned)r;
            s_dst[p] = dst;
        }
    }
    __syncthreads();
    int sc = N_EDGES - e0; if (sc > NB_CHUNK) sc = NB_CHUNK;
#pragma unroll
    for (int k = 0; k < NB_CHUNK / 256; ++k) {
        int j = t + k * 256;
        if (j < sc) tmp[s_dst[j]] = s_val[j];
    }
}

__global__ __launch_bounds__(256) void bscan_kernel(const int* __restrict__ bfill,
                                                    int* __restrict__ bbase) {
    __shared__ int s[256];
    int t = threadIdx.x;
    int cnt = 0;
    if (t < NBUCK) {
        cnt = bfill[t] - t * CAP;
        if (cnt > CAP) cnt = CAP;
    }
    s[t] = cnt;
    __syncthreads();
    for (int o = 1; o < 256; o <<= 1) {
        int u = (t >= o) ? s[t - o] : 0;
        __syncthreads();
        s[t] += u;
        __syncthreads();
    }
    if (t < NBUCK) bbase[t] = s[t] - cnt;
}

__global__ __launch_bounds__(256) void sort_kernel(const unsigned* __restrict__ tmp,
                                                   const int* __restrict__ bfill,
                                                   const int* __restrict__ bbase,
                                                   int* __restrict__ csr,
                                                   float* __restrict__ dinv,
                                                   int* __restrict__ ssrc) {
    __shared__ int s_cnt[BW];
    __shared__ int s_pair[256];
    __shared__ int s_off[BW];
    __shared__ int s_cur[BW];
    __shared__ int s_stage[CAP];
    int b = blockIdx.x, t = threadIdx.x;
    int wbeg = b * BW;
    int wn = N_NODES - wbeg; if (wn > BW) wn = BW;
    int nE = bfill[b] - b * CAP; if (nE > CAP) nE = CAP;
    const unsigned* T = tmp + (size_t)b * CAP;
    int base = bbase[b];

    for (int i = t; i < BW; i += 256) s_cnt[i] = 0;
    __syncthreads();
    for (int i = t; i < nE; i += 256) atomicAdd(&s_cnt[T[i] >> 17], 1);
    __syncthreads();
    int a0 = s_cnt[2 * t], a1 = s_cnt[2 * t + 1];
    s_pair[t] = a0 + a1;
    __syncthreads();
    for (int o = 1; o < 256; o <<= 1) {
        int u = (t >= o) ? s_pair[t - o] : 0;
        __syncthreads();
        s_pair[t] += u;
        __syncthreads();
    }
    int pre = s_pair[t] - (a0 + a1);
    s_off[2 * t] = pre;      s_off[2 * t + 1] = pre + a0;
    s_cur[2 * t] = pre;      s_cur[2 * t + 1] = pre + a0;
    __syncthreads();
    for (int i = t; i < wn; i += 256) {
        csr[wbeg + i]  = base + s_off[i];
        dinv[wbeg + i] = rsqrtf((float)(s_cnt[i] + 1));  // +1 = self loop
    }
    for (int i = t; i < nE; i += 256) {
        unsigned v = T[i];
        int p = atomicAdd(&s_cur[v >> 17], 1);
        s_stage[p] = (int)(v & 0x1FFFFu);
    }
    __syncthreads();
    for (int i = t; i < nE; i += 256) ssrc[base + i] = s_stage[i];
}

__global__ __launch_bounds__(256) void bounds_kernel(const int* __restrict__ batch,
                                                     int* __restrict__ gstart) {
    int i = blockIdx.x * 256 + threadIdx.x;
    if (i >= N_NODES) return;
    int b  = batch[i];
    int bp = (i == 0) ? -1 : batch[i - 1];
    for (int g = bp + 1; g <= b; ++g) gstart[g] = i;
    if (i == N_NODES - 1) {
        for (int g = b + 1; g <= N_GRAPHS; ++g) gstart[g] = N_NODES;
    }
}

// ---------------- aggregate: out[c] = dinv[c] * (g[c] + sum g[src]) ----------
// one QUARTER-WAVE (16 lanes x 16 B = one 256 B row) per node, independent
// 4-deep edge unroll per quarter -> a wave keeps ~16 gathers in flight
// regardless of per-node degree; no cross-lane reduction; direct stores.
__global__ __launch_bounds__(256) void agg_kernel(const ushort* __restrict__ g,
                                                  ushort* __restrict__ out,
                                                  const int* __restrict__ off,
                                                  const int* __restrict__ ssrc,
                                                  const float* __restrict__ dinv) {
    int node = blockIdx.x * 16 + (threadIdx.x >> 4);  // quarter-wave id
    int l    = threadIdx.x & 15;
    const uint4* hp = (const uint4*)g;  // row = 16 uint4 (256 B)

    // self loop: + g[node]
    uint4 v = hp[(size_t)node * 16 + l];
    float acc[8];
    acc[0] = bf2f_lo(v.x); acc[1] = bf2f_hi(v.x);
    acc[2] = bf2f_lo(v.y); acc[3] = bf2f_hi(v.y);
    acc[4] = bf2f_lo(v.z); acc[5] = bf2f_hi(v.z);
    acc[6] = bf2f_lo(v.w); acc[7] = bf2f_hi(v.w);

    int e = off[node], end = off[node + 1];
    for (; e + 3 < end; e += 4) {
        int s0 = ssrc[e], s1 = ssrc[e + 1], s2 = ssrc[e + 2], s3 = ssrc[e + 3];
        uint4 v0 = hp[(size_t)s0 * 16 + l];
        uint4 v1 = hp[(size_t)s1 * 16 + l];
        uint4 v2 = hp[(size_t)s2 * 16 + l];
        uint4 v3 = hp[(size_t)s3 * 16 + l];
        acc[0] += bf2f_lo(v0.x); acc[1] += bf2f_hi(v0.x);
        acc[2] += bf2f_lo(v0.y); acc[3] += bf2f_hi(v0.y);
        acc[4] += bf2f_lo(v0.z); acc[5] += bf2f_hi(v0.z);
        acc[6] += bf2f_lo(v0.w); acc[7] += bf2f_hi(v0.w);
        acc[0] += bf2f_lo(v1.x); acc[1] += bf2f_hi(v1.x);
        acc[2] += bf2f_lo(v1.y); acc[3] += bf2f_hi(v1.y);
        acc[4] += bf2f_lo(v1.z); acc[5] += bf2f_hi(v1.z);
        acc[6] += bf2f_lo(v1.w); acc[7] += bf2f_hi(v1.w);
        acc[0] += bf2f_lo(v2.x); acc[1] += bf2f_hi(v2.x);
        acc[2] += bf2f_lo(v2.y); acc[3] += bf2f_hi(v2.y);
        acc[4] += bf2f_lo(v2.z); acc[5] += bf2f_hi(v2.z);
        acc[6] += bf2f_lo(v2.w); acc[7] += bf2f_hi(v2.w);
        acc[0] += bf2f_lo(v3.x); acc[1] += bf2f_hi(v3.x);
        acc[2] += bf2f_lo(v3.y); acc[3] += bf2f_hi(v3.y);
        acc[4] += bf2f_lo(v3.z); acc[5] += bf2f_hi(v3.z);
        acc[6] += bf2f_lo(v3.w); acc[7] += bf2f_hi(v3.w);
    }
    if (e + 1 < end) {  // 2-deep remainder
        int s0 = ssrc[e], s1 = ssrc[e + 1];
        uint4 v0 = hp[(size_t)s0 * 16 + l];
        uint4 v1 = hp[(size_t)s1 * 16 + l];
        acc[0] += bf2f_lo(v0.x); acc[1] += bf2f_hi(v0.x);
        acc[2] += bf2f_lo(v0.y); acc[3] += bf2f_hi(v0.y);
        acc[4] += bf2f_lo(v0.z); acc[5] += bf2f_hi(v0.z);
        acc[6] += bf2f_lo(v0.w); acc[7] += bf2f_hi(v0.w);
        acc[0] += bf2f_lo(v1.x); acc[1] += bf2f_hi(v1.x);
        acc[2] += bf2f_lo(v1.y); acc[3] += bf2f_hi(v1.y);
        acc[4] += bf2f_lo(v1.z); acc[5] += bf2f_hi(v1.z);
        acc[6] += bf2f_lo(v1.w); acc[7] += bf2f_hi(v1.w);
        e += 2;
    }
    if (e < end) {
        int s = ssrc[e];
        uint4 v1 = hp[(size_t)s * 16 + l];
        acc[0] += bf2f_lo(v1.x); acc[1] += bf2f_hi(v1.x);
        acc[2] += bf2f_lo(v1.y); acc[3] += bf2f_hi(v1.y);
        acc[4] += bf2f_lo(v1.z); acc[5] += bf2f_hi(v1.z);
        acc[6] += bf2f_lo(v1.w); acc[7] += bf2f_hi(v1.w);
    }

    float d = dinv[node];
    uint4 ov;
    ov.x = (uint)f2bf(acc[0] * d) | ((uint)f2bf(acc[1] * d) << 16);
    ov.y = (uint)f2bf(acc[2] * d) | ((uint)f2bf(acc[3] * d) << 16);
    ov.z = (uint)f2bf(acc[4] * d) | ((uint)f2bf(acc[5] * d) << 16);
    ov.w = (uint)f2bf(acc[6] * d) | ((uint)f2bf(acc[7] * d) << 16);
    ((uint4*)out)[(size_t)node * 16 + l] = ov;
}

// ---------------- GEMM via bf16 MFMA, WT staged in LDS -----------------------
#define WPAD 136
__global__ __launch_bounds__(256) void gemm_mfma(const ushort* __restrict__ A,
                                                 const ushort* __restrict__ WT,
                                                 const float* __restrict__ bias,
                                                 const float* __restrict__ dinv,
                                                 ushort* __restrict__ out,
                                                 int mode) {
    __shared__ ushort sW[128 * WPAD];
    int t = threadIdx.x;
    {   // stage WT: 2048 uint4 transfers (16 per row), coalesced
#pragma unroll
        for (int j = 0; j < 8; ++j) {
            int idx = t + j * 256;      // 0..2047
            int r = idx >> 4, qq = idx & 15;
            uint4 v = *(const uint4*)(WT + (size_t)r * 128 + qq * 8);
            *(uint4*)(sW + (size_t)r * WPAD + qq * 8) = v;
        }
    }
    __syncthreads();

    int lane = t & 63;
    int wv   = t >> 6;
    int m0   = blockIdx.x * 128 + wv * 32;
    int l15  = lane & 15;
    int kq   = (lane >> 4) * 8;
    int r0 = m0 + l15, r1 = m0 + 16 + l15;
    if (r0 >= N_NODES) r0 = N_NODES - 1;  // clamp loads; stores guarded
    if (r1 >= N_NODES) r1 = N_NODES - 1;

    f32x4 acc0[8], acc1[8];
#pragma unroll
    for (int n = 0; n < 8; ++n) {
        acc0[n] = (f32x4){0.f, 0.f, 0.f, 0.f};
        acc1[n] = (f32x4){0.f, 0.f, 0.f, 0.f};
    }

#pragma unroll
    for (int k0 = 0; k0 < 128; k0 += 32) {
        bf16x8 a0 = *(const bf16x8*)(A + (size_t)r0 * 128 + k0 + kq);
        bf16x8 a1 = *(const bf16x8*)(A + (size_t)r1 * 128 + k0 + kq);
#pragma unroll
        for (int n = 0; n < 8; ++n) {
            bf16x8 b = *(const bf16x8*)(sW + (size_t)(n * 16 + l15) * WPAD + k0 + kq);
            acc0[n] = __builtin_amdgcn_mfma_f32_16x16x32_bf16(a0, b, acc0[n], 0, 0, 0);
            acc1[n] = __builtin_amdgcn_mfma_f32_16x16x32_bf16(a1, b, acc1[n], 0, 0, 0);
        }
    }

#pragma unroll
    for (int sub = 0; sub < 2; ++sub) {
        int orow = m0 + sub * 16 + (lane >> 4) * 4;
        float sc[4];
#pragma unroll
        for (int r = 0; r < 4; ++r) {
            int m = orow + r;
            sc[r] = (mode && m < N_NODES) ? dinv[m] : 1.0f;
        }
#pragma unroll
        for (int n = 0; n < 8; ++n) {
            int col = n * 16 + l15;
            float bv = bias[col];
            f32x4 av = sub ? acc1[n] : acc0[n];
#pragma unroll
            for (int r = 0; r < 4; ++r) {
                int m = orow + r;
                if (m < N_NODES) {
                    float v = av[r] + bv;
                    if (mode) v = fmaxf(v, 0.f) * sc[r];
                    out[(size_t)m * 128 + col] = f2bf(v);
                }
            }
        }
    }
}

// ---------------- fused pooling + MLP head (one block per graph) -------------

__global__ __launch_bounds__(256) void pool_mlp(const ushort* __restrict__ h,
                                                const int* __restrict__ gstart,
                                                const float* __restrict__ w1,
                                                const float* __restrict__ b1,
                                                const float* __restrict__ w2,
                                                const float* __restrict__ b2,
                                                float* __restrict__ out) {
    __shared__ float part[4][128];
    __shared__ float mean[128];
    __shared__ float hid[100];
    int g = blockIdx.x;
    int s = gstart[g], e2 = gstart[g + 1];
    int p     = threadIdx.x & 63;
    int which = threadIdx.x >> 6;
    const uint* hu = (const uint*)h;

    float a0 = 0.f, a1 = 0.f;
    for (int n = s + which; n < e2; n += 4) {
        uint v = hu[(size_t)n * 64 + p];
        a0 += bf2f_lo(v);
        a1 += bf2f_hi(v);
    }
    part[which][2 * p]     = a0;
    part[which][2 * p + 1] = a1;
    __syncthreads();
    if (which == 0) {
        float c = fmaxf((float)(e2 - s), 1.0f);
        mean[2 * p]     = (part[0][2 * p] + part[1][2 * p] + part[2][2 * p] + part[3][2 * p]) / c;
        mean[2 * p + 1] = (part[0][2 * p + 1] + part[1][2 * p + 1] + part[2][2 * p + 1] + part[3][2 * p + 1]) / c;
    }
    __syncthreads();
    int t = threadIdx.x;
    if (t < 100) {
        float s1 = b1[t];
        for (int k = 0; k < 128; ++k) s1 = fmaf(mean[k], w1[k * 100 + t], s1);
        hid[t] = fmaxf(s1, 0.f);
    }
    __syncthreads();
    if (t < 4) {
        float s2 = b2[t];
        for (int j = 0; j < 100; ++j) s2 = fmaf(hid[j], w2[j * 4 + t], s2);
        out[(size_t)g * 4 + t] = s2;
    }
}

// ---------------- launch ----------------

extern "C" void kernel_launch(void* const* d_in, const int* in_sizes, int n_in,
                              void* d_out, int out_size, void* d_ws, size_t ws_size,
                              hipStream_t stream) {
    const float* x   = (const float*)d_in[0];
    const float* Ws  = (const float*)d_in[1];
    const float* bs  = (const float*)d_in[2];
    const float* w1  = (const float*)d_in[3];
    const float* b1  = (const float*)d_in[4];
    const float* w2  = (const float*)d_in[5];
    const float* b2  = (const float*)d_in[6];
    const int*   ei  = (const int*)d_in[7];
    const int*   bat = (const int*)d_in[8];
    float* outp = (float*)d_out;

    char* p = (char*)d_ws;
    auto take = [&](size_t bytes) -> void* {
        void* r = (void*)p;
        p += (bytes + 255) & ~(size_t)255;
        return r;
    };
    int*      csr    = (int*)take((size_t)(N_NODES + 1) * 4);
    float*    dinv   = (float*)take((size_t)N_NODES * 4);
    int*      bfill  = (int*)take((size_t)NBUCK * 4);
    int*      bbase  = (int*)take((size_t)NBUCK * 4);
    unsigned* tmp    = (unsigned*)take((size_t)NBUCK * CAP * 4);
    int*      ssrc   = (int*)take((size_t)N_EDGES * 4);
    ushort*   xb     = (ushort*)take((size_t)N_NODES * 128 * 2);
    ushort*   hb     = (ushort*)take((size_t)N_NODES * 128 * 2);
    ushort*   aggb   = (ushort*)take((size_t)N_NODES * 128 * 2);
    ushort*   WT     = (ushort*)take((size_t)4 * 128 * 128 * 2);
    int*      gstart = (int*)take((size_t)(N_GRAPHS + 1) * 4);

    const int* row = ei;
    const int* col = ei + N_EDGES;

    initb_kernel<<<1, 256, 0, stream>>>(bfill, csr);
    bin_kernel<<<(N_EDGES + NB_CHUNK - 1) / NB_CHUNK, 256, 0, stream>>>(row, col, bfill, tmp);
    bscan_kernel<<<1, 256, 0, stream>>>(bfill, bbase);
    sort_kernel<<<NBUCK, 256, 0, stream>>>(tmp, bfill, bbase, csr, dinv, ssrc);
    cvt_x<<<12500, 256, 0, stream>>>(x, dinv, xb);
    cvt_w<<<256, 256, 0, stream>>>(Ws, WT);
    bounds_kernel<<<(N_NODES + 255) / 256, 256, 0, stream>>>(bat, gstart);

    const ushort* hin = xb;
    for (int L = 0; L < 4; ++L) {
        agg_kernel<<<N_NODES / 16, 256, 0, stream>>>(hin, aggb, csr, ssrc, dinv);
        gemm_mfma<<<(N_NODES + 127) / 128, 256, 0, stream>>>(
            aggb, WT + (size_t)L * 128 * 128, bs + (size_t)L * 128, dinv, hb, (L < 3) ? 1 : 0);
        hin = hb;
    }
    pool_mlp<<<N_GRAPHS, 256, 0, stream>>>(hb, gstart, w1, b1, w2, b2, outp);
}